// Round 12
// baseline (2295.553 us; speedup 1.0000x reference)
//
#include <hip/hip_runtime.h>
#include <math.h>

#define NPTS 16384
#define KNN 32
#define NB 8
#define CD 83
#define PDIM 35

__device__ __forceinline__ int bval(const int* __restrict__ p, int i, int is32) {
    return is32 ? p[i] : p[2 * i];
}

// ===== numpy universal-intrinsics f32 sin/cos (loops_trigonometric.dispatch) =====
__device__ __forceinline__ float np_sincos_f32(float x, int compute_cos) {
    const float two_over_pi = 0x1.45f306p-1f;
    const float c1 = -0x1.921fb0p+00f;
    const float c2 = -0x1.5110b4p-22f;
    const float c3 = -0x1.846988p-48f;
    const float rint_cvt = 12582912.0f;
    float q = __fsub_rn(__fadd_rn(__fmul_rn(x, two_over_pi), rint_cvt), rint_cvt);
    float rx = __builtin_fmaf(q, c1, x);
    rx = __builtin_fmaf(q, c2, rx);
    rx = __builtin_fmaf(q, c3, rx);
    float r2 = __fmul_rn(rx, rx);
    float yc = __builtin_fmaf(0x1.98e616p-16f, r2, -0x1.6c06dcp-10f);
    yc = __builtin_fmaf(yc, r2, 0x1.55553cp-05f);
    yc = __builtin_fmaf(yc, r2, -0x1.000000p-1f);
    yc = __builtin_fmaf(yc, r2, 0x1.000000p+0f);
    float ys = __builtin_fmaf(0x1.7d3bbcp-19f, r2, -0x1.a06bbap-13f);
    ys = __builtin_fmaf(ys, r2, 0x1.11119ap-07f);
    ys = __builtin_fmaf(ys, r2, -0x1.555556p-03f);
    ys = __fmul_rn(ys, r2);
    ys = __builtin_fmaf(ys, rx, rx);
    int iq = (int)q + compute_cos;
    float res = ((iq & 1) == 0) ? ys : yc;
    if (iq & 2) res = __int_as_float(__float_as_int(res) ^ 0x80000000u);
    return res;
}

// ===== numpy FLOAT_exp (loops_exponent_log.dispatch — Cephes expf, FMA form) =====
__device__ __forceinline__ float np_exp_f32(float x) {
    const float log2e = 1.442695040f;       // NPY_LOG2Ef
    const float rint_cvt = 12582912.0f;
    if (x < -87.33654f) return 0.0f;        // underflow mask path
    float q = __fsub_rn(__fadd_rn(__fmul_rn(x, log2e), rint_cvt), rint_cvt);  // rint
    float r = __builtin_fmaf(q, -0.693359375f, x);       // x - q*C1 (cephes C1)
    r = __builtin_fmaf(q, 2.12194440e-4f, r);            // - q*C2 (C2 = -2.12194440e-4)
    float y = 1.9875691500e-4f;
    y = __builtin_fmaf(y, r, 1.3981999507e-3f);
    y = __builtin_fmaf(y, r, 8.3334519073e-3f);
    y = __builtin_fmaf(y, r, 4.1665795894e-2f);
    y = __builtin_fmaf(y, r, 1.6666665459e-1f);
    y = __builtin_fmaf(y, r, 5.0000001201e-1f);
    float r2 = __fmul_rn(r, r);
    y = __builtin_fmaf(y, r2, r);                        // y*r^2 + r
    y = __fadd_rn(y, 1.0f);                              // + 1
    int iq = (int)q;
    float sc = __int_as_float((127 + iq) << 23);         // 2^q
    return __fmul_rn(y, sc);
}

// ===== OpenBLAS sgemv_t 8-lane order (n==1 gemm->gemv forwarding) =====
__device__ __forceinline__ float np_gemv32(const float* h, const float* __restrict__ w) {
    float a0 = 0.f, a1 = 0.f, a2 = 0.f, a3 = 0.f, a4 = 0.f, a5 = 0.f, a6 = 0.f, a7 = 0.f;
    #pragma unroll
    for (int t = 0; t < 32; t += 8) {
        a0 = __builtin_fmaf(h[t],     w[t],     a0);
        a1 = __builtin_fmaf(h[t + 1], w[t + 1], a1);
        a2 = __builtin_fmaf(h[t + 2], w[t + 2], a2);
        a3 = __builtin_fmaf(h[t + 3], w[t + 3], a3);
        a4 = __builtin_fmaf(h[t + 4], w[t + 4], a4);
        a5 = __builtin_fmaf(h[t + 5], w[t + 5], a5);
        a6 = __builtin_fmaf(h[t + 6], w[t + 6], a6);
        a7 = __builtin_fmaf(h[t + 7], w[t + 7], a7);
    }
    float s0 = __fadd_rn(a0, a4);
    float s1 = __fadd_rn(a1, a5);
    float s2 = __fadd_rn(a2, a6);
    float s3 = __fadd_rn(a3, a7);
    return __fadd_rn(__fadd_rn(s0, s1), __fadd_rn(s2, s3));
}

__global__ void k_flag(const int* __restrict__ batch32, int* __restrict__ flag) {
    if (threadIdx.x == 0) flag[0] = (batch32[NPTS - 1] != 0) ? 1 : 0;
}

__global__ void k_bounds(const int* __restrict__ batch, const int* __restrict__ flag,
                         int* __restrict__ seg) {
    int b = threadIdx.x;
    if (b > NB) return;
    int is32 = flag[0];
    int lo = 0, hi = NPTS;
    while (lo < hi) { int mid = (lo + hi) >> 1; if (bval(batch, mid, is32) < b) lo = mid + 1; else hi = mid; }
    seg[b] = lo;
}

__global__ void __launch_bounds__(256) k_front(
    const float* __restrict__ x, const float* __restrict__ pos,
    const float* __restrict__ w1f, const float* __restrict__ b1f,
    const float* __restrict__ w2f, const float* __restrict__ b2f,
    const float* __restrict__ w1p, const float* __restrict__ b1p,
    const float* __restrict__ w2p, const float* __restrict__ b2p,
    float* __restrict__ comb)
{
    int i = blockIdx.x * 256 + threadIdx.x;
    float enc[32];
    float px = pos[i * 3];
    #pragma unroll
    for (int f = 0; f < 16; ++f) {
        float fbf = (float)((double)f * (9.0 / 63.0) + 1.0);
        float a = __fmul_rn(px, fbf);
        enc[2 * f] = np_sincos_f32(a, 0);
        enc[2 * f + 1] = np_sincos_f32(a, 1);
    }
    float h[32], hr[32];
    #pragma unroll
    for (int j = 0; j < 32; ++j) h[j] = 0.0f;
    for (int k = 0; k < 16; ++k) {
        float v = x[i * 16 + k];
        #pragma unroll
        for (int j = 0; j < 32; ++j) h[j] = __builtin_fmaf(v, w1f[k * 32 + j], h[j]);
    }
    for (int e = 0; e < 32; ++e) {
        float v = enc[e];
        #pragma unroll
        for (int j = 0; j < 32; ++j) h[j] = __builtin_fmaf(v, w1f[(16 + e) * 32 + j], h[j]);
    }
    #pragma unroll
    for (int j = 0; j < 32; ++j) hr[j] = fmaxf(__fadd_rn(h[j], b1f[j]), 0.0f);
    float fw = __fadd_rn(np_gemv32(hr, w2f), b2f[0]);

    #pragma unroll
    for (int j = 0; j < 32; ++j) h[j] = 0.0f;
    for (int c = 0; c < 3; ++c) {
        float v = pos[i * 3 + c];
        #pragma unroll
        for (int j = 0; j < 32; ++j) h[j] = __builtin_fmaf(v, w1p[c * 32 + j], h[j]);
    }
    for (int e = 0; e < 32; ++e) {
        float v = enc[e];
        #pragma unroll
        for (int j = 0; j < 32; ++j) h[j] = __builtin_fmaf(v, w1p[(3 + e) * 32 + j], h[j]);
    }
    #pragma unroll
    for (int j = 0; j < 32; ++j) hr[j] = fmaxf(__fadd_rn(h[j], b1p[j]), 0.0f);
    float pw = __fadd_rn(np_gemv32(hr, w2p), b2p[0]);

    float m = fmaxf(fw, pw);
    float e0 = np_exp_f32(__fsub_rn(fw, m));
    float e1 = np_exp_f32(__fsub_rn(pw, m));
    float s = __fadd_rn(e0, e1);
    float sw0 = __fdiv_rn(e0, s);   // scales feat
    float sw1 = __fdiv_rn(e1, s);   // scales pe

    float* out = comb + (long)i * CD;
    out[0] = __fmul_rn(pos[i * 3], sw1);
    out[1] = __fmul_rn(pos[i * 3 + 1], sw1);
    out[2] = __fmul_rn(pos[i * 3 + 2], sw1);
    #pragma unroll
    for (int e = 0; e < 32; ++e) out[3 + e] = __fmul_rn(enc[e], sw1);
    for (int k = 0; k < 16; ++k) out[35 + k] = __fmul_rn(x[i * 16 + k], sw0);
    #pragma unroll
    for (int e = 0; e < 32; ++e) out[51 + e] = __fmul_rn(enc[e], sw0);
}

__global__ void __launch_bounds__(128) k_stats(
    const float* __restrict__ comb, const int* __restrict__ seg,
    float* __restrict__ meanb, float* __restrict__ denb)
{
    int b = blockIdx.x;
    int d = threadIdx.x;
    if (d >= CD) return;
    int start = seg[b], end = seg[b + 1];
    float sum = 0.0f, ss = 0.0f;
    for (int r = start; r < end; ++r) {
        float c = comb[(long)r * CD + d];
        sum = __fadd_rn(sum, c);
        ss = __fadd_rn(ss, __fmul_rn(c, c));
    }
    float cnt = (float)(end - start);
    float mn = __fdiv_rn(sum, fmaxf(cnt, 1.0f));
    float num = __fsub_rn(ss, __fmul_rn(__fmul_rn(cnt, mn), mn));
    float var = __fdiv_rn(num, fmaxf(__fsub_rn(cnt, 1.0f), 1.0f));
    if (var < 0.0f) var = 0.0f;
    meanb[b * CD + d] = mn;
    denb[b * CD + d] = __fadd_rn(__fsqrt_rn(var), 1e-8f);
}

__global__ void __launch_bounds__(256) k_z(
    float* __restrict__ comb, const int* __restrict__ batch, const int* __restrict__ flag,
    const float* __restrict__ meanb, const float* __restrict__ denb,
    float* __restrict__ sqb)
{
    int r = blockIdx.x * 256 + threadIdx.x;
    int b = bval(batch, r, flag[0]);
    const float* mb = meanb + b * CD;
    const float* db = denb + b * CD;
    float* row = comb + (long)r * CD;
    float p[CD];
    for (int d = 0; d < CD; ++d) {
        float zz = __fdiv_rn(__fsub_rn(row[d], mb[d]), db[d]);
        row[d] = zz;
        p[d] = __fmul_rn(zz, zz);
    }
    float r0 = p[0], r1 = p[1], r2 = p[2], r3 = p[3];
    float r4 = p[4], r5 = p[5], r6 = p[6], r7 = p[7];
    #pragma unroll
    for (int i = 8; i < 80; i += 8) {
        r0 = __fadd_rn(r0, p[i]);     r1 = __fadd_rn(r1, p[i + 1]);
        r2 = __fadd_rn(r2, p[i + 2]); r3 = __fadd_rn(r3, p[i + 3]);
        r4 = __fadd_rn(r4, p[i + 4]); r5 = __fadd_rn(r5, p[i + 5]);
        r6 = __fadd_rn(r6, p[i + 6]); r7 = __fadd_rn(r7, p[i + 7]);
    }
    float res = __fadd_rn(__fadd_rn(__fadd_rn(r0, r1), __fadd_rn(r2, r3)),
                          __fadd_rn(__fadd_rn(r4, r5), __fadd_rn(r6, r7)));
    res = __fadd_rn(res, p[80]);
    res = __fadd_rn(res, p[81]);
    res = __fadd_rn(res, p[82]);
    sqb[r] = res;
}

// ---- KNN: sgemm-order f32 dot, d2 = (sqi+sqj) - 2*dot; top-32, ties -> lower index ----
__global__ void __launch_bounds__(128) k_knn(
    const float* __restrict__ z, const float* __restrict__ sqb,
    const int* __restrict__ batch, const int* __restrict__ flag,
    const int* __restrict__ seg, int* __restrict__ out)
{
    int i = blockIdx.x * 128 + threadIdx.x;
    int bi = bval(batch, i, flag[0]);
    int lo = seg[bi], hi = seg[bi + 1];
    float zq[CD];
    for (int d = 0; d < CD; ++d) zq[d] = z[(long)i * CD + d];
    float sqi = sqb[i];
    float kd[KNN]; int ki[KNN];
    #pragma unroll
    for (int k = 0; k < KNN; ++k) { kd[k] = INFINITY; ki[k] = 0x7fffffff; }
    for (int j = lo; j < hi; ++j) {
        const float* zj = z + (long)j * CD;
        float acc = 0.0f;
        for (int d = 0; d < CD; ++d) acc = __builtin_fmaf(zq[d], zj[d], acc);
        float dist = __fsub_rn(__fadd_rn(sqi, sqb[j]), __fmul_rn(2.0f, acc));
        if (dist < kd[KNN - 1]) {
            kd[KNN - 1] = dist; ki[KNN - 1] = j;
            #pragma unroll
            for (int k = KNN - 2; k >= 0; --k) {
                if (kd[k + 1] < kd[k]) {
                    float td = kd[k]; kd[k] = kd[k + 1]; kd[k + 1] = td;
                    int ti = ki[k]; ki[k] = ki[k + 1]; ki[k + 1] = ti;
                }
            }
        }
    }
    int* orow = out;
    int* ocol = out + (long)NPTS * KNN;
    #pragma unroll
    for (int k = 0; k < KNN; ++k) {
        orow[(long)i * KNN + k] = i;
        ocol[(long)i * KNN + k] = ki[k];
    }
}

extern "C" void kernel_launch(void* const* d_in, const int* in_sizes, int n_in,
                              void* d_out, int out_size, void* d_ws, size_t ws_size,
                              hipStream_t stream)
{
    const float* x   = (const float*)d_in[0];
    const float* pos = (const float*)d_in[1];
    const int* batch = (const int*)d_in[2];
    const float* w1f = (const float*)d_in[3];
    const float* b1f = (const float*)d_in[4];
    const float* w2f = (const float*)d_in[5];
    const float* b2f = (const float*)d_in[6];
    const float* w1p = (const float*)d_in[7];
    const float* b1p = (const float*)d_in[8];
    const float* w2p = (const float*)d_in[9];
    const float* b2p = (const float*)d_in[10];

    char* ws = (char*)d_ws;
    float* comb  = (float*)(ws);                // N*83*4 = 5,439,488 (combined, then z in place)
    float* sqb   = (float*)(ws + 5439488);      // N*4    = 65,536
    float* meanb = (float*)(ws + 5505024);      // 664*4  = 2,656
    float* denb  = (float*)(ws + 5507680);      // 664*4  = 2,656
    int*   seg   = (int*)  (ws + 5510400);      // 9 ints
    int*   flag  = (int*)  (ws + 5510464);      // 1 int
    int* out = (int*)d_out;

    hipLaunchKernelGGL(k_flag, dim3(1), dim3(64), 0, stream, batch, flag);
    hipLaunchKernelGGL(k_bounds, dim3(1), dim3(16), 0, stream, batch, flag, seg);
    hipLaunchKernelGGL(k_front, dim3(NPTS / 256), dim3(256), 0, stream,
                       x, pos, w1f, b1f, w2f, b2f, w1p, b1p, w2p, b2p, comb);
    hipLaunchKernelGGL(k_stats, dim3(NB), dim3(128), 0, stream, comb, seg, meanb, denb);
    hipLaunchKernelGGL(k_z, dim3(NPTS / 256), dim3(256), 0, stream, comb, batch, flag, meanb, denb, sqb);
    hipLaunchKernelGGL(k_knn, dim3(NPTS / 128), dim3(128), 0, stream, comb, sqb, batch, flag, seg, out);
}